// Round 3
// baseline (652.947 us; speedup 1.0000x reference)
//
#include <hip/hip_runtime.h>
#include <hip/hip_bf16.h>

// Problem constants
#define Bc   128
#define Nc   16
#define Fc   20
#define Dc   4
#define Ec   256
#define Hc   128
#define NBc  10
#define BNc  (Bc*Nc)          // 2048
#define Mrows (BNc*Fc)        // 40960

typedef __attribute__((ext_vector_type(8))) short short8;
typedef __attribute__((ext_vector_type(4))) float f32x4;

static __device__ __forceinline__ unsigned short f2bf(float f) {
    union { float f; unsigned u; } v; v.f = f;
    unsigned r = v.u + 0x7fff + ((v.u >> 16) & 1);   // RNE
    return (unsigned short)(r >> 16);
}

static __device__ __forceinline__ float fast_tanh(float v) {
    // tanh(v) = 1 - 2/(exp(2v)+1); exp via v_exp_f32, div via v_rcp_f32
    float t = __expf(2.f * v);
    return 1.f - 2.f * __builtin_amdgcn_rcpf(t + 1.f);
}
static __device__ __forceinline__ float fast_sigmoid(float v) {
    return __builtin_amdgcn_rcpf(1.f + __expf(-v));
}

// ---------------------------------------------------------------------------
// K0: transpose + bf16-convert a weight matrix  w[256][768] -> wT[768][256]
// ---------------------------------------------------------------------------
__global__ __launch_bounds__(256)
void k_wprep(const float* __restrict__ w, unsigned short* __restrict__ wT) {
    int n = blockIdx.x;        // 0..767
    int k = threadIdx.x;       // 0..255
    wT[n * 256 + k] = f2bf(w[k * 768 + n]);
}

// ---------------------------------------------------------------------------
// K1: build x in bf16, layout [f][bn][e]  (f-major so GRU steps are dense)
// ---------------------------------------------------------------------------
__global__ __launch_bounds__(256)
void k_build_x(const float* __restrict__ ent, const int* __restrict__ bfeat,
               const float* __restrict__ Wp, const float* __restrict__ bp,
               const float* __restrict__ Wr, const float* __restrict__ br,
               const float* __restrict__ emb, unsigned short* __restrict__ x) {
    int r   = blockIdx.x;          // 0..40959  (= bn*Fc + f)
    int f   = r % Fc;
    int bn  = r / Fc;
    int i   = bn % Nc;
    int b   = bn / Nc;
    int tid = threadIdx.x;         // 0..255

    __shared__ float sE[Nc][Dc];
    __shared__ float sDiff[Nc][Dc];
    __shared__ float sDist[Nc];

    if (tid < Nc * Dc) {
        int j = tid >> 2, d = tid & 3;
        sE[j][d] = ent[((b * Nc + j) * Fc + f) * Dc + d];
    }
    __syncthreads();
    if (tid < Nc) {
        float d0 = sE[i][0] - sE[tid][0];
        float d1 = sE[i][1] - sE[tid][1];
        float d2 = sE[i][2] - sE[tid][2];
        float d3 = sE[i][3] - sE[tid][3];
        sDiff[tid][0] = d0; sDiff[tid][1] = d1;
        sDiff[tid][2] = d2; sDiff[tid][3] = d3;
        sDist[tid] = sqrtf(d0 * d0 + d1 * d1);   // only dims 0,1 per reference
    }
    __syncthreads();

    float bemb = 0.f;
    #pragma unroll
    for (int k = 0; k < NBc; ++k) {
        int idx = bfeat[r * NBc + k];
        bemb += emb[idx * Ec + tid];
    }

    float entv;
    if (tid < Hc) {
        float v = bp[tid];
        #pragma unroll
        for (int d = 0; d < Dc; ++d) v = fmaf(sE[i][d], Wp[d * Hc + tid], v);
        entv = fast_tanh(v);
    } else {
        int h = tid - Hc;
        float w0 = Wr[0 * Hc + h], w1 = Wr[1 * Hc + h], w2 = Wr[2 * Hc + h];
        float w3 = Wr[3 * Hc + h], w4 = Wr[4 * Hc + h], bb = br[h];
        float s = 0.f;
        #pragma unroll
        for (int j = 0; j < Nc; ++j) {
            if (j == i) continue;           // diagonal skipped in reference
            float v = bb;
            v = fmaf(sDiff[j][0], w0, v);
            v = fmaf(sDiff[j][1], w1, v);
            v = fmaf(sDiff[j][2], w2, v);
            v = fmaf(sDiff[j][3], w3, v);
            v = fmaf(sDist[j],    w4, v);
            s += fast_tanh(v);
        }
        entv = s;
    }
    x[((size_t)f * BNc + bn) * Ec + tid] = f2bf(entv + bemb);
}

// ---------------------------------------------------------------------------
// K2: fully fused GRU with on-the-fly input projection.
//   gates = x_f @ w_ih + h @ w_hh (+ biases); r,z share an accumulator,
//   n keeps x- and h-parts split (r gates only the h-part).
// 64 blocks x 32 rows; 1024 threads = 16 waves; wave w owns e in
// [w*16,(w+1)*16) => gate cols {e, e+256, e+512}; 2 row-tiles per wave.
// h master in registers (fp32); bf16 copy in LDS as the MFMA A-operand.
// ---------------------------------------------------------------------------
#define HSTR 264   // LDS row stride in bf16 (528 B) -> aligned, conflict-mild

__global__ __launch_bounds__(1024)
void k_gru_fused(const unsigned short* __restrict__ x,     // [Fc][BNc][Ec]
                 const unsigned short* __restrict__ wihT,  // [768][256]
                 const unsigned short* __restrict__ whhT,  // [768][256]
                 const float* __restrict__ bih, const float* __restrict__ bhh,
                 float* __restrict__ out) {
    __shared__ __align__(16) unsigned short hb[32 * HSTR];
    int bn0 = blockIdx.x * 32;
    int w = threadIdx.x >> 6, l = threadIdx.x & 63;
    int lr = l & 15, lg = l >> 4;
    int e = w * 16 + lr;

    // h == 0 at f=0; zero LDS so the uniform loop's h-MFMAs contribute 0
    for (int t = threadIdx.x; t < 32 * HSTR; t += 1024) hb[t] = 0;

    float bR  = bih[e]          + bhh[e];
    float bZ  = bih[Ec + e]     + bhh[Ec + e];
    float bNi = bih[2 * Ec + e];
    float bNh = bhh[2 * Ec + e];

    const unsigned short* wiR = wihT + (size_t)e * Ec;
    const unsigned short* wiZ = wihT + (size_t)(Ec + e) * Ec;
    const unsigned short* wiN = wihT + (size_t)(2 * Ec + e) * Ec;
    const unsigned short* whR = whhT + (size_t)e * Ec;
    const unsigned short* whZ = whhT + (size_t)(Ec + e) * Ec;
    const unsigned short* whN = whhT + (size_t)(2 * Ec + e) * Ec;

    float hold[8] = {};   // [rt*4 + j]
    __syncthreads();

    for (int f = 0; f < Fc; ++f) {
        const unsigned short* xf = x + ((size_t)f * BNc + bn0) * Ec;
        f32x4 aR0 = {}, aR1 = {}, aZ0 = {}, aZ1 = {};
        f32x4 aNx0 = {}, aNx1 = {}, aNh0 = {}, aNh1 = {};

        #pragma unroll 2
        for (int kk = 0; kk < 8; ++kk) {
            int k0 = kk * 32 + lg * 8;
            short8 a0 = *(const short8*)(xf + (size_t)lr * Ec + k0);
            short8 a1 = *(const short8*)(xf + (size_t)(16 + lr) * Ec + k0);
            short8 h0 = *(const short8*)&hb[lr * HSTR + k0];
            short8 h1 = *(const short8*)&hb[(16 + lr) * HSTR + k0];
            short8 uR = *(const short8*)(wiR + k0);
            short8 uZ = *(const short8*)(wiZ + k0);
            short8 uN = *(const short8*)(wiN + k0);
            short8 vR = *(const short8*)(whR + k0);
            short8 vZ = *(const short8*)(whZ + k0);
            short8 vN = *(const short8*)(whN + k0);
            aR0  = __builtin_amdgcn_mfma_f32_16x16x32_bf16(a0, uR, aR0, 0, 0, 0);
            aR0  = __builtin_amdgcn_mfma_f32_16x16x32_bf16(h0, vR, aR0, 0, 0, 0);
            aR1  = __builtin_amdgcn_mfma_f32_16x16x32_bf16(a1, uR, aR1, 0, 0, 0);
            aR1  = __builtin_amdgcn_mfma_f32_16x16x32_bf16(h1, vR, aR1, 0, 0, 0);
            aZ0  = __builtin_amdgcn_mfma_f32_16x16x32_bf16(a0, uZ, aZ0, 0, 0, 0);
            aZ0  = __builtin_amdgcn_mfma_f32_16x16x32_bf16(h0, vZ, aZ0, 0, 0, 0);
            aZ1  = __builtin_amdgcn_mfma_f32_16x16x32_bf16(a1, uZ, aZ1, 0, 0, 0);
            aZ1  = __builtin_amdgcn_mfma_f32_16x16x32_bf16(h1, vZ, aZ1, 0, 0, 0);
            aNx0 = __builtin_amdgcn_mfma_f32_16x16x32_bf16(a0, uN, aNx0, 0, 0, 0);
            aNx1 = __builtin_amdgcn_mfma_f32_16x16x32_bf16(a1, uN, aNx1, 0, 0, 0);
            aNh0 = __builtin_amdgcn_mfma_f32_16x16x32_bf16(h0, vN, aNh0, 0, 0, 0);
            aNh1 = __builtin_amdgcn_mfma_f32_16x16x32_bf16(h1, vN, aNh1, 0, 0, 0);
        }
        __syncthreads();   // all waves done reading hb

        bool last = (f == Fc - 1);
        #define EPILOGUE(AR, AZ, ANX, ANH, RT)                                   \
        {                                                                        \
            _Pragma("unroll")                                                    \
            for (int j = 0; j < 4; ++j) {                                        \
                float rg = fast_sigmoid(AR[j] + bR);                             \
                float zg = fast_sigmoid(AZ[j] + bZ);                             \
                float hn = ANH[j] + bNh;                                         \
                float ng = fast_tanh(ANX[j] + bNi + rg * hn);                    \
                float h  = (1.f - zg) * ng + zg * hold[RT * 4 + j];              \
                hold[RT * 4 + j] = h;                                            \
                int row = RT * 16 + lg * 4 + j;                                  \
                if (last) out[(size_t)(bn0 + row) * Ec + e] = h;                 \
                else      hb[row * HSTR + e] = f2bf(h);                          \
            }                                                                    \
        }
        EPILOGUE(aR0, aZ0, aNx0, aNh0, 0)
        EPILOGUE(aR1, aZ1, aNx1, aNh1, 1)
        #undef EPILOGUE

        __syncthreads();   // hb writes visible before next step's MFMA reads
    }
}

// ---------------------------------------------------------------------------
extern "C" void kernel_launch(void* const* d_in, const int* in_sizes, int n_in,
                              void* d_out, int out_size, void* d_ws, size_t ws_size,
                              hipStream_t stream) {
    const float* ent  = (const float*)d_in[0];
    const int*   bfeat= (const int*)  d_in[1];
    const float* Wp   = (const float*)d_in[2];
    const float* bp   = (const float*)d_in[3];
    const float* Wr   = (const float*)d_in[4];
    const float* br   = (const float*)d_in[5];
    const float* emb  = (const float*)d_in[6];
    const float* wih  = (const float*)d_in[7];
    const float* bih  = (const float*)d_in[8];
    const float* whh  = (const float*)d_in[9];
    const float* bhh  = (const float*)d_in[10];
    float* out = (float*)d_out;

    char* ws = (char*)d_ws;
    unsigned short* x    = (unsigned short*)ws;                        // 21 MB
    unsigned short* wihT = (unsigned short*)(ws + (size_t)Mrows * Ec * 2);
    unsigned short* whhT = wihT + (size_t)768 * 256;

    k_wprep<<<768, 256, 0, stream>>>(wih, wihT);
    k_wprep<<<768, 256, 0, stream>>>(whh, whhT);

    k_build_x<<<Mrows, 256, 0, stream>>>(ent, bfeat, Wp, bp, Wr, br, emb, x);

    k_gru_fused<<<BNc / 32, 1024, 0, stream>>>(x, wihT, whhT, bih, bhh, out);
}

// Round 4
// 411.230 us; speedup vs baseline: 1.5878x; 1.5878x over previous
//
#include <hip/hip_runtime.h>
#include <hip/hip_bf16.h>

// Problem constants
#define Bc   128
#define Nc   16
#define Fc   20
#define Dc   4
#define Ec   256
#define Hc   128
#define NBc  10
#define BNc  (Bc*Nc)          // 2048
#define Mrows (BNc*Fc)        // 40960

// GRU geometry
#define GB    64              // GRU blocks
#define GROWS 32              // rows per GRU block
#define HSTR  264             // LDS row stride (shorts): 528 B -> 2-way (free) bank pattern

typedef __attribute__((ext_vector_type(8))) short short8;
typedef __attribute__((ext_vector_type(4))) float f32x4;

static __device__ __forceinline__ unsigned short f2bf(float f) {
    union { float f; unsigned u; } v; v.f = f;
    unsigned r = v.u + 0x7fff + ((v.u >> 16) & 1);   // RNE
    return (unsigned short)(r >> 16);
}
static __device__ __forceinline__ float fast_tanh(float v) {
    float t = __expf(2.f * v);
    return 1.f - 2.f * __builtin_amdgcn_rcpf(t + 1.f);
}
static __device__ __forceinline__ float fast_sigmoid(float v) {
    return __builtin_amdgcn_rcpf(1.f + __expf(-v));
}

// ---------------------------------------------------------------------------
// K0: transpose + bf16-convert a weight matrix  w[256][768] -> wT[768][256]
// ---------------------------------------------------------------------------
__global__ __launch_bounds__(256)
void k_wprep(const float* __restrict__ w, unsigned short* __restrict__ wT) {
    int n = blockIdx.x;        // 0..767
    int k = threadIdx.x;       // 0..255
    wT[n * 256 + k] = f2bf(w[k * 768 + n]);
}

// ---------------------------------------------------------------------------
// K1: build x in bf16, layout [f][bn][e]
// ---------------------------------------------------------------------------
__global__ __launch_bounds__(256)
void k_build_x(const float* __restrict__ ent, const int* __restrict__ bfeat,
               const float* __restrict__ Wp, const float* __restrict__ bp,
               const float* __restrict__ Wr, const float* __restrict__ br,
               const float* __restrict__ emb, unsigned short* __restrict__ x) {
    int r   = blockIdx.x;          // = bn*Fc + f
    int f   = r % Fc;
    int bn  = r / Fc;
    int i   = bn % Nc;
    int b   = bn / Nc;
    int tid = threadIdx.x;

    __shared__ float sE[Nc][Dc];
    __shared__ float sDiff[Nc][Dc];
    __shared__ float sDist[Nc];

    if (tid < Nc * Dc) {
        int j = tid >> 2, d = tid & 3;
        sE[j][d] = ent[((b * Nc + j) * Fc + f) * Dc + d];
    }
    __syncthreads();
    if (tid < Nc) {
        float d0 = sE[i][0] - sE[tid][0];
        float d1 = sE[i][1] - sE[tid][1];
        float d2 = sE[i][2] - sE[tid][2];
        float d3 = sE[i][3] - sE[tid][3];
        sDiff[tid][0] = d0; sDiff[tid][1] = d1;
        sDiff[tid][2] = d2; sDiff[tid][3] = d3;
        sDist[tid] = sqrtf(d0 * d0 + d1 * d1);   // only dims 0,1 per reference
    }
    __syncthreads();

    float bemb = 0.f;
    #pragma unroll
    for (int k = 0; k < NBc; ++k) {
        int idx = bfeat[r * NBc + k];
        bemb += emb[idx * Ec + tid];
    }

    float entv;
    if (tid < Hc) {
        float v = bp[tid];
        #pragma unroll
        for (int d = 0; d < Dc; ++d) v = fmaf(sE[i][d], Wp[d * Hc + tid], v);
        entv = fast_tanh(v);
    } else {
        int h = tid - Hc;
        float w0 = Wr[0 * Hc + h], w1 = Wr[1 * Hc + h], w2 = Wr[2 * Hc + h];
        float w3 = Wr[3 * Hc + h], w4 = Wr[4 * Hc + h], bb = br[h];
        float s = 0.f;
        #pragma unroll
        for (int j = 0; j < Nc; ++j) {
            if (j == i) continue;           // diagonal skipped in reference
            float v = bb;
            v = fmaf(sDiff[j][0], w0, v);
            v = fmaf(sDiff[j][1], w1, v);
            v = fmaf(sDiff[j][2], w2, v);
            v = fmaf(sDiff[j][3], w3, v);
            v = fmaf(sDist[j],    w4, v);
            s += fast_tanh(v);
        }
        entv = s;
    }
    x[((size_t)f * BNc + bn) * Ec + tid] = f2bf(entv + bemb);
}

// ---------------------------------------------------------------------------
// K2: gi = x @ w_ih stored in MFMA C-FRAGMENT layout:
//   gi[((f*GB+g)*8+w)*12*256 + t*256 + l*4 + j],  t = rt*6 + et*3 + gate.
// Grid (GB, Fc), 512 threads = 8 waves; wave w owns e in [w*32,(w+1)*32).
// ---------------------------------------------------------------------------
__global__ __launch_bounds__(512, 2)
void k_gi_frag(const unsigned short* __restrict__ x,
               const unsigned short* __restrict__ wihT,
               float* __restrict__ gi) {
    int g = blockIdx.x, f = blockIdx.y;
    int w = threadIdx.x >> 6, l = threadIdx.x & 63;
    int lr = l & 15, lg = l >> 4;
    int bn0 = g * GROWS;
    const unsigned short* xf = x + ((size_t)f * BNc + bn0) * Ec;

    f32x4 acc[12] = {};
    #pragma unroll 2
    for (int kk = 0; kk < 8; ++kk) {
        int k0 = kk * 32 + lg * 8;
        short8 a0 = *(const short8*)(xf + (size_t)lr * Ec + k0);
        short8 a1 = *(const short8*)(xf + (size_t)(16 + lr) * Ec + k0);
        #pragma unroll
        for (int et = 0; et < 2; ++et) {
            #pragma unroll
            for (int gt = 0; gt < 3; ++gt) {
                int col = gt * Ec + w * 32 + et * 16 + lr;
                short8 bf = *(const short8*)(wihT + (size_t)col * Ec + k0);
                int t = et * 3 + gt;
                acc[t]     = __builtin_amdgcn_mfma_f32_16x16x32_bf16(a0, bf, acc[t],     0, 0, 0);
                acc[6 + t] = __builtin_amdgcn_mfma_f32_16x16x32_bf16(a1, bf, acc[6 + t], 0, 0, 0);
            }
        }
    }
    float* dst = gi + ((((size_t)f * GB + g) * 8 + w) * 12) * 256 + l * 4;
    #pragma unroll
    for (int t = 0; t < 12; ++t) *(f32x4*)(dst + (size_t)t * 256) = acc[t];
}

// ---------------------------------------------------------------------------
// K3: fused GRU. 64 blocks x 32 rows, 512 threads = 8 waves (2/SIMD).
// Wave w owns e in [w*32,(w+1)*32) => gate cols {e, e+256, e+512}: the
// (r,z,n) triplet for an h-element lands in the same lane & reg index.
// h master in fp32 registers; bf16 copy in LDS is the MFMA A-operand.
// gi read as 12 coalesced float4 per wave per step (fragment layout).
// ---------------------------------------------------------------------------
__global__ __launch_bounds__(512, 2)
void k_gru_fused(const float* __restrict__ gi,
                 const unsigned short* __restrict__ whhT,
                 const float* __restrict__ bih, const float* __restrict__ bhh,
                 float* __restrict__ out) {
    __shared__ __align__(16) unsigned short hb[GROWS * HSTR];
    int g = blockIdx.x;
    int w = threadIdx.x >> 6, l = threadIdx.x & 63;
    int lr = l & 15, lg = l >> 4;
    int bn0 = g * GROWS;

    for (int t = threadIdx.x; t < GROWS * HSTR; t += 512) hb[t] = 0;

    float bR[2], bZ[2], bNi[2], bNh[2];
    #pragma unroll
    for (int et = 0; et < 2; ++et) {
        int e = w * 32 + et * 16 + lr;
        bR[et]  = bih[e]          + bhh[e];
        bZ[et]  = bih[Ec + e]     + bhh[Ec + e];
        bNi[et] = bih[2 * Ec + e];
        bNh[et] = bhh[2 * Ec + e];
    }
    float hold[2][2][4] = {};
    __syncthreads();

    const size_t fstride = (size_t)GB * 8 * 12 * 256;
    const float* gbase = gi + (((size_t)g * 8 + w) * 12) * 256 + l * 4;

    for (int f = 0; f < Fc; ++f) {
        // coalesced gi fragments for this step; latency hidden under K-loop
        f32x4 gv[12];
        const float* gp = gbase + (size_t)f * fstride;
        #pragma unroll
        for (int t = 0; t < 12; ++t) gv[t] = *(const f32x4*)(gp + (size_t)t * 256);

        // gh = h @ w_hh  (bf16 MFMA; A from LDS, B streamed from L2)
        f32x4 acc[12] = {};
        #pragma unroll 2
        for (int kk = 0; kk < 8; ++kk) {
            int k0 = kk * 32 + lg * 8;
            short8 h0 = *(const short8*)&hb[lr * HSTR + k0];
            short8 h1 = *(const short8*)&hb[(16 + lr) * HSTR + k0];
            #pragma unroll
            for (int et = 0; et < 2; ++et) {
                #pragma unroll
                for (int gt = 0; gt < 3; ++gt) {
                    int col = gt * Ec + w * 32 + et * 16 + lr;
                    short8 bf = *(const short8*)(whhT + (size_t)col * Ec + k0);
                    int t = et * 3 + gt;
                    acc[t]     = __builtin_amdgcn_mfma_f32_16x16x32_bf16(h0, bf, acc[t],     0, 0, 0);
                    acc[6 + t] = __builtin_amdgcn_mfma_f32_16x16x32_bf16(h1, bf, acc[6 + t], 0, 0, 0);
                }
            }
        }
        __syncthreads();   // all waves done reading hb

        bool last = (f == Fc - 1);
        #pragma unroll
        for (int rt = 0; rt < 2; ++rt) {
            #pragma unroll
            for (int et = 0; et < 2; ++et) {
                int tR = rt * 6 + et * 3 + 0;
                int tZ = rt * 6 + et * 3 + 1;
                int tN = rt * 6 + et * 3 + 2;
                int e  = w * 32 + et * 16 + lr;
                #pragma unroll
                for (int j = 0; j < 4; ++j) {
                    float rg = fast_sigmoid(gv[tR][j] + acc[tR][j] + bR[et]);
                    float zg = fast_sigmoid(gv[tZ][j] + acc[tZ][j] + bZ[et]);
                    float ng = fast_tanh(gv[tN][j] + bNi[et] + rg * (acc[tN][j] + bNh[et]));
                    float h  = (1.f - zg) * ng + zg * hold[rt][et][j];
                    hold[rt][et][j] = h;
                    int row = rt * 16 + lg * 4 + j;
                    if (last) out[(size_t)(bn0 + row) * Ec + e] = h;
                    else      hb[row * HSTR + e] = f2bf(h);
                }
            }
        }
        __syncthreads();   // hb writes visible before next step's MFMA reads
    }
}

// ---------------------------------------------------------------------------
extern "C" void kernel_launch(void* const* d_in, const int* in_sizes, int n_in,
                              void* d_out, int out_size, void* d_ws, size_t ws_size,
                              hipStream_t stream) {
    const float* ent  = (const float*)d_in[0];
    const int*   bfeat= (const int*)  d_in[1];
    const float* Wp   = (const float*)d_in[2];
    const float* bp   = (const float*)d_in[3];
    const float* Wr   = (const float*)d_in[4];
    const float* br   = (const float*)d_in[5];
    const float* emb  = (const float*)d_in[6];
    const float* wih  = (const float*)d_in[7];
    const float* bih  = (const float*)d_in[8];
    const float* whh  = (const float*)d_in[9];
    const float* bhh  = (const float*)d_in[10];
    float* out = (float*)d_out;

    char* ws = (char*)d_ws;
    unsigned short* x    = (unsigned short*)ws;                        // 21 MB
    float*          gi   = (float*)(ws + (size_t)Mrows * Ec * 2);      // 126 MB
    unsigned short* wihT = (unsigned short*)(ws + (size_t)Mrows * Ec * 2
                                                + (size_t)Mrows * 768 * 4);
    unsigned short* whhT = wihT + (size_t)768 * 256;

    k_wprep<<<768, 256, 0, stream>>>(wih, wihT);
    k_wprep<<<768, 256, 0, stream>>>(whh, whhT);

    k_build_x<<<Mrows, 256, 0, stream>>>(ent, bfeat, Wp, bp, Wr, br, emb, x);

    dim3 g2(GB, Fc);
    k_gi_frag<<<g2, 512, 0, stream>>>(x, wihT, gi);

    k_gru_fused<<<GB, 512, 0, stream>>>(gi, whhT, bih, bhh, out);
}

// Round 5
// 156.161 us; speedup vs baseline: 4.1813x; 2.6334x over previous
//
#include <hip/hip_runtime.h>
#include <hip/hip_bf16.h>

// Problem constants
#define Bc   128
#define Nc   16
#define Fc   20
#define Dc   4
#define Ec   256
#define Hc   128
#define NBc  10
#define BNc  (Bc*Nc)          // 2048
#define Mrows (BNc*Fc)        // 40960

#define NG   128              // row-groups of 16 rows (GRU/gi blocks)

typedef __attribute__((ext_vector_type(8))) short short8;
typedef __attribute__((ext_vector_type(4))) float f32x4;

static __device__ __forceinline__ unsigned short f2bf(float f) {
    union { float f; unsigned u; } v; v.f = f;
    unsigned r = v.u + 0x7fff + ((v.u >> 16) & 1);   // RNE
    return (unsigned short)(r >> 16);
}
static __device__ __forceinline__ float bf2f(unsigned u16) {
    union { unsigned u; float f; } v; v.u = u16 << 16; return v.f;
}
static __device__ __forceinline__ float bfhi2f(unsigned u) {   // high short already in place
    union { unsigned uu; float f; } v; v.uu = u & 0xffff0000u; return v.f;
}
static __device__ __forceinline__ float fast_tanh(float v) {
    float t = __expf(2.f * v);
    return 1.f - 2.f * __builtin_amdgcn_rcpf(t + 1.f);
}
static __device__ __forceinline__ float fast_sigmoid(float v) {
    return __builtin_amdgcn_rcpf(1.f + __expf(-v));
}

// ---------------------------------------------------------------------------
// K0: transpose + bf16-convert a weight matrix  w[256][768] -> wT[768][256]
// ---------------------------------------------------------------------------
__global__ __launch_bounds__(256)
void k_wprep(const float* __restrict__ w, unsigned short* __restrict__ wT) {
    int n = blockIdx.x;        // 0..767
    int k = threadIdx.x;       // 0..255
    wT[n * 256 + k] = f2bf(w[k * 768 + n]);
}

// ---------------------------------------------------------------------------
// K1: build x in bf16, layout [f][bn][e]
// ---------------------------------------------------------------------------
__global__ __launch_bounds__(256)
void k_build_x(const float* __restrict__ ent, const int* __restrict__ bfeat,
               const float* __restrict__ Wp, const float* __restrict__ bp,
               const float* __restrict__ Wr, const float* __restrict__ br,
               const float* __restrict__ emb, unsigned short* __restrict__ x) {
    int r   = blockIdx.x;          // = bn*Fc + f
    int f   = r % Fc;
    int bn  = r / Fc;
    int i   = bn % Nc;
    int b   = bn / Nc;
    int tid = threadIdx.x;

    __shared__ float sE[Nc][Dc];
    __shared__ float sDiff[Nc][Dc];
    __shared__ float sDist[Nc];

    if (tid < Nc * Dc) {
        int j = tid >> 2, d = tid & 3;
        sE[j][d] = ent[((b * Nc + j) * Fc + f) * Dc + d];
    }
    __syncthreads();
    if (tid < Nc) {
        float d0 = sE[i][0] - sE[tid][0];
        float d1 = sE[i][1] - sE[tid][1];
        float d2 = sE[i][2] - sE[tid][2];
        float d3 = sE[i][3] - sE[tid][3];
        sDiff[tid][0] = d0; sDiff[tid][1] = d1;
        sDiff[tid][2] = d2; sDiff[tid][3] = d3;
        sDist[tid] = sqrtf(d0 * d0 + d1 * d1);   // only dims 0,1 per reference
    }
    __syncthreads();

    float bemb = 0.f;
    #pragma unroll
    for (int k = 0; k < NBc; ++k) {
        int idx = bfeat[r * NBc + k];
        bemb += emb[idx * Ec + tid];
    }

    float entv;
    if (tid < Hc) {
        float v = bp[tid];
        #pragma unroll
        for (int d = 0; d < Dc; ++d) v = fmaf(sE[i][d], Wp[d * Hc + tid], v);
        entv = fast_tanh(v);
    } else {
        int h = tid - Hc;
        float w0 = Wr[0 * Hc + h], w1 = Wr[1 * Hc + h], w2 = Wr[2 * Hc + h];
        float w3 = Wr[3 * Hc + h], w4 = Wr[4 * Hc + h], bb = br[h];
        float s = 0.f;
        #pragma unroll
        for (int j = 0; j < Nc; ++j) {
            if (j == i) continue;           // diagonal skipped in reference
            float v = bb;
            v = fmaf(sDiff[j][0], w0, v);
            v = fmaf(sDiff[j][1], w1, v);
            v = fmaf(sDiff[j][2], w2, v);
            v = fmaf(sDiff[j][3], w3, v);
            v = fmaf(sDist[j],    w4, v);
            s += fast_tanh(v);
        }
        entv = s;
    }
    x[((size_t)f * BNc + bn) * Ec + tid] = f2bf(entv + bemb);
}

// ---------------------------------------------------------------------------
// Shared geometry for K2/K3:
//  block = 1024 thr = 16 waves; wave w owns e in [w*16,(w+1)*16);
//  its 3 gate-cols tiles: col(t) = t*256 + w*16 + lr  (t = r,z,n).
//  B-fragments (24 per lane, 16 B each): kk 0..5 in VGPRs, kk 6..7 in LDS.
//  C layout: col = lr, row = lg*4 + j.
// gi stored bf16 in fragment order: [f][g][w][t][lane][4].
// ---------------------------------------------------------------------------
#define WL_IDX(w, t, kkr, l) (((((w) * 3 + (t)) * 2 + (kkr)) * 64 + (l)) * 8)

// K2: gi = x @ w_ih + b_ih  (bias folded here). Grid (NG, 2); 10 f per block.
__global__ __launch_bounds__(1024, 4)
void k_gi_frag(const unsigned short* __restrict__ x,
               const unsigned short* __restrict__ wihT,
               const float* __restrict__ bih,
               unsigned short* __restrict__ gi) {
    __shared__ __align__(16) unsigned short wl[16 * 3 * 2 * 64 * 8];  // 96 KB
    int g = blockIdx.x, fh = blockIdx.y;
    int w = threadIdx.x >> 6, l = threadIdx.x & 63;
    int lr = l & 15, lg = l >> 4;
    int bn0 = g * 16;

    short8 wr[3][6];
    float bv[3];
    #pragma unroll
    for (int t = 0; t < 3; ++t) {
        const unsigned short* wp = wihT + (size_t)(t * 256 + w * 16 + lr) * 256 + lg * 8;
        #pragma unroll
        for (int kk = 0; kk < 6; ++kk) wr[t][kk] = *(const short8*)(wp + kk * 32);
        #pragma unroll
        for (int kk = 6; kk < 8; ++kk)
            *(short8*)&wl[WL_IDX(w, t, kk - 6, l)] = *(const short8*)(wp + kk * 32);
        bv[t] = bih[t * 256 + w * 16 + lr];
    }
    __syncthreads();

    for (int fi = 0; fi < 10; ++fi) {
        int f = fh * 10 + fi;
        const unsigned short* xf = x + ((size_t)f * BNc + bn0) * Ec + lg * 8;
        f32x4 acc[3] = {};
        #pragma unroll
        for (int kk = 0; kk < 8; ++kk) {
            short8 a = *(const short8*)(xf + (size_t)lr * Ec + kk * 32);
            short8 b0, b1, b2;
            if (kk < 6) { b0 = wr[0][kk]; b1 = wr[1][kk]; b2 = wr[2][kk]; }
            else {
                b0 = *(const short8*)&wl[WL_IDX(w, 0, kk - 6, l)];
                b1 = *(const short8*)&wl[WL_IDX(w, 1, kk - 6, l)];
                b2 = *(const short8*)&wl[WL_IDX(w, 2, kk - 6, l)];
            }
            acc[0] = __builtin_amdgcn_mfma_f32_16x16x32_bf16(a, b0, acc[0], 0, 0, 0);
            acc[1] = __builtin_amdgcn_mfma_f32_16x16x32_bf16(a, b1, acc[1], 0, 0, 0);
            acc[2] = __builtin_amdgcn_mfma_f32_16x16x32_bf16(a, b2, acc[2], 0, 0, 0);
        }
        #pragma unroll
        for (int t = 0; t < 3; ++t) {
            uint2 o;
            o.x = (unsigned)f2bf(acc[t][0] + bv[t]) | ((unsigned)f2bf(acc[t][1] + bv[t]) << 16);
            o.y = (unsigned)f2bf(acc[t][2] + bv[t]) | ((unsigned)f2bf(acc[t][3] + bv[t]) << 16);
            size_t idx = ((((size_t)f * NG + g) * 48) + w * 3 + t) * 256 + l * 4;
            *(uint2*)(gi + idx) = o;
        }
    }
}

// K3: fused GRU, weights resident. Grid NG; one barrier per step.
__global__ __launch_bounds__(1024, 4)
void k_gru(const unsigned short* __restrict__ gi,
           const unsigned short* __restrict__ whhT,
           const float* __restrict__ bhh,
           float* __restrict__ out) {
    __shared__ __align__(16) unsigned short hb[2][16 * 256];          // 16 KB, XOR-swizzled
    __shared__ __align__(16) unsigned short wl[16 * 3 * 2 * 64 * 8];  // 96 KB
    int g = blockIdx.x;
    int w = threadIdx.x >> 6, l = threadIdx.x & 63;
    int lr = l & 15, lg = l >> 4;
    int bn0 = g * 16;

    for (int t = threadIdx.x; t < 16 * 256; t += 1024) hb[0][t] = 0;

    short8 wr[3][6];
    #pragma unroll
    for (int t = 0; t < 3; ++t) {
        const unsigned short* wp = whhT + (size_t)(t * 256 + w * 16 + lr) * 256 + lg * 8;
        #pragma unroll
        for (int kk = 0; kk < 6; ++kk) wr[t][kk] = *(const short8*)(wp + kk * 32);
        #pragma unroll
        for (int kk = 6; kk < 8; ++kk)
            *(short8*)&wl[WL_IDX(w, t, kk - 6, l)] = *(const short8*)(wp + kk * 32);
    }
    float bhR = bhh[w * 16 + lr];
    float bhZ = bhh[256 + w * 16 + lr];
    float bhN = bhh[512 + w * 16 + lr];
    __syncthreads();

    float hold[4] = {};
    const unsigned short* gp = gi + ((size_t)g * 48 + w * 3) * 256 + l * 4;
    const size_t fstr = (size_t)NG * 48 * 256;

    for (int f = 0; f < Fc; ++f) {
        // the only global loads in the loop: 3 x 8 B, consumed after the MFMAs
        uint2 gv0 = *(const uint2*)(gp);
        uint2 gv1 = *(const uint2*)(gp + 256);
        uint2 gv2 = *(const uint2*)(gp + 512);
        gp += fstr;

        const char* hbuf = (const char*)hb[f & 1];
        f32x4 acc[3] = {};
        #pragma unroll
        for (int kk = 0; kk < 8; ++kk) {
            int bo = (lr * 512 + kk * 64 + lg * 16) ^ ((lr & 7) << 4);
            short8 a = *(const short8*)(hbuf + bo);
            short8 b0, b1, b2;
            if (kk < 6) { b0 = wr[0][kk]; b1 = wr[1][kk]; b2 = wr[2][kk]; }
            else {
                b0 = *(const short8*)&wl[WL_IDX(w, 0, kk - 6, l)];
                b1 = *(const short8*)&wl[WL_IDX(w, 1, kk - 6, l)];
                b2 = *(const short8*)&wl[WL_IDX(w, 2, kk - 6, l)];
            }
            acc[0] = __builtin_amdgcn_mfma_f32_16x16x32_bf16(a, b0, acc[0], 0, 0, 0);
            acc[1] = __builtin_amdgcn_mfma_f32_16x16x32_bf16(a, b1, acc[1], 0, 0, 0);
            acc[2] = __builtin_amdgcn_mfma_f32_16x16x32_bf16(a, b2, acc[2], 0, 0, 0);
        }

        float giR[4] = { bf2f(gv0.x & 0xffffu), bfhi2f(gv0.x), bf2f(gv0.y & 0xffffu), bfhi2f(gv0.y) };
        float giZ[4] = { bf2f(gv1.x & 0xffffu), bfhi2f(gv1.x), bf2f(gv1.y & 0xffffu), bfhi2f(gv1.y) };
        float giN[4] = { bf2f(gv2.x & 0xffffu), bfhi2f(gv2.x), bf2f(gv2.y & 0xffffu), bfhi2f(gv2.y) };

        bool last = (f == Fc - 1);
        char* wbuf = (char*)hb[(f + 1) & 1];
        #pragma unroll
        for (int j = 0; j < 4; ++j) {
            float rg = fast_sigmoid(giR[j] + acc[0][j] + bhR);
            float zg = fast_sigmoid(giZ[j] + acc[1][j] + bhZ);
            float ng = fast_tanh(giN[j] + rg * (acc[2][j] + bhN));
            float h  = (1.f - zg) * ng + zg * hold[j];
            hold[j] = h;
            int row = lg * 4 + j;
            if (last) {
                out[(size_t)(bn0 + row) * Ec + w * 16 + lr] = h;
            } else {
                int bo = (row * 512 + (w * 16 + lr) * 2) ^ ((row & 7) << 4);
                *(unsigned short*)(wbuf + bo) = f2bf(h);
            }
        }
        if (!last) __syncthreads();   // h writes visible before next step's reads
    }
}

// ---------------------------------------------------------------------------
extern "C" void kernel_launch(void* const* d_in, const int* in_sizes, int n_in,
                              void* d_out, int out_size, void* d_ws, size_t ws_size,
                              hipStream_t stream) {
    const float* ent  = (const float*)d_in[0];
    const int*   bfeat= (const int*)  d_in[1];
    const float* Wp   = (const float*)d_in[2];
    const float* bp   = (const float*)d_in[3];
    const float* Wr   = (const float*)d_in[4];
    const float* br   = (const float*)d_in[5];
    const float* emb  = (const float*)d_in[6];
    const float* wih  = (const float*)d_in[7];
    const float* bih  = (const float*)d_in[8];
    const float* whh  = (const float*)d_in[9];
    const float* bhh  = (const float*)d_in[10];
    float* out = (float*)d_out;

    char* ws = (char*)d_ws;
    unsigned short* x    = (unsigned short*)ws;                          // 21 MB
    unsigned short* gi   = (unsigned short*)(ws + (size_t)Mrows * Ec * 2); // 63 MB
    unsigned short* wihT = (unsigned short*)(ws + (size_t)Mrows * Ec * 2
                                                + (size_t)Mrows * 768 * 2);
    unsigned short* whhT = wihT + (size_t)768 * 256;

    k_wprep<<<768, 256, 0, stream>>>(wih, wihT);
    k_wprep<<<768, 256, 0, stream>>>(whh, whhT);

    k_build_x<<<Mrows, 256, 0, stream>>>(ent, bfeat, Wp, bp, Wr, br, emb, x);

    dim3 g2(NG, 2);
    k_gi_frag<<<g2, 1024, 0, stream>>>(x, wihT, bih, gi);

    k_gru<<<NG, 1024, 0, stream>>>(gi, whhT, bhh, out);
}